// Round 5
// baseline (978.494 us; speedup 1.0000x reference)
//
#include <hip/hip_runtime.h>

#define N_NODES 50000
#define N_EDGES 1600000
#define F_IN 256
#define F_OUT 64
#define ALPHA 0.2f

#define NB 782        // buckets of 64 nodes (50000/64 -> 782)
#define NSUB 8        // sub-buckets (by blockIdx&7 ~ XCD) for write locality
#define CAP 512       // per (bucket,sub) capacity; expected 256 +- 15
#define OF_CAP 8192   // overflow list capacity (normally unused)

// ---------------------------------------------------------------------------
// Kernel A: Wh = x @ W. W slice held in REGISTERS (wave w owns K rows
// [64w,64w+64), col=lane -> 64 VGPRs). x read as wave-uniform float4 (scalar
// pipe) -- no ds_read in the K loop, so lgkmcnt waits order only the x loads.
// Cross-wave K-reduction via 8KB LDS. Fused s_src/s_dst epilogue.
// ---------------------------------------------------------------------------
__global__ __launch_bounds__(256) void gat_gemm(
    const float* __restrict__ x, const float* __restrict__ W,
    const float* __restrict__ a, float* __restrict__ Wh,
    float* __restrict__ s_src, float* __restrict__ s_dst)
{
    __shared__ float part[4 * 512];
    const int t = threadIdx.x;
    const int lane = t & 63;
    const int w = t >> 6;

    float wreg[64];
    #pragma unroll
    for (int j = 0; j < 64; ++j)
        wreg[j] = W[(size_t)(w * 64 + j) * F_OUT + lane];   // coalesced, once

    const float a0 = a[lane];
    const float a1 = a[F_OUT + lane];

    for (int c = blockIdx.x; c < N_NODES / 8; c += gridDim.x) {
        const int node0 = c * 8;
        float accs[8];
        #pragma unroll
        for (int n = 0; n < 8; ++n) {
            const float4* __restrict__ xp =
                (const float4*)(x + (size_t)(node0 + n) * F_IN + w * 64);
            float accA = 0.f, accB = 0.f;   // 2 chains to halve dep latency
            #pragma unroll
            for (int j = 0; j < 16; ++j) {
                const float4 xk = xp[j];    // wave-uniform -> s_load_dwordx4
                accA = fmaf(xk.x, wreg[4 * j + 0], accA);
                accB = fmaf(xk.y, wreg[4 * j + 1], accB);
                accA = fmaf(xk.z, wreg[4 * j + 2], accA);
                accB = fmaf(xk.w, wreg[4 * j + 3], accB);
            }
            accs[n] = accA + accB;
        }
        __syncthreads();   // WAR: part[] still being read by previous finalize
        #pragma unroll
        for (int n = 0; n < 8; ++n)
            part[w * 512 + n * 64 + lane] = accs[n];
        __syncthreads();
        #pragma unroll
        for (int r = 0; r < 2; ++r) {
            const int idx = r * 256 + t;   // = r*256 + w*64 + lane
            const int n = idx >> 6;        // node-in-chunk = r*4 + w
            const float v = part[idx] + part[512 + idx] +
                            part[1024 + idx] + part[1536 + idx];
            Wh[(size_t)(node0 + n) * F_OUT + lane] = v;   // coalesced
            float p = v * a0, q = v * a1;
            #pragma unroll
            for (int off = 32; off > 0; off >>= 1) {
                p += __shfl_down(p, off);
                q += __shfl_down(q, off);
            }
            if (lane == 0) { s_src[node0 + n] = p; s_dst[node0 + n] = q; }
        }
    }
}

// ---------------------------------------------------------------------------
// Pass 1: bucket edges by src>>6 into NSUB sub-buckets keyed by blockIdx&7
// (~XCD id under round-robin dispatch) -> each sub-bucket's tail line is
// written by one XCD's L2 and fills before writeback. Entry packs
// (s&63)<<16 | dst (dst < 50000 < 2^16). Fixed capacity + overflow list.
// ---------------------------------------------------------------------------
__global__ __launch_bounds__(256) void gat_bucket(
    const int* __restrict__ edge, int* __restrict__ cnt,
    unsigned int* __restrict__ arr, int* __restrict__ of_cnt,
    int2* __restrict__ of_list)
{
    const int e = blockIdx.x * 256 + threadIdx.x;   // grid exactly covers E
    const int s = edge[e];
    const int d = edge[N_EDGES + e];
    const int ci = (s >> 6) * NSUB + (blockIdx.x & 7);
    const int pos = atomicAdd(&cnt[ci], 1);
    if (pos < CAP) {
        arr[(size_t)ci * CAP + pos] = ((unsigned)(s & 63) << 16) | (unsigned)d;
    } else {
        const int op = atomicAdd(of_cnt, 1);
        if (op < OF_CAP) of_list[op] = make_int2(s, d);
    }
}

// ---------------------------------------------------------------------------
// Pass 2: block per 64-node bucket. LDS accumulators acc[64][65] (padded to
// break bank conflicts) + LDS rowsum, LDS float atomics. Waves process
// sub-buckets {w, w+4}. Quarter-wave per edge: 16 lanes x float4 = one
// 256B Wh gather per edge, 1 VMEM inst / 4 edges. Fused divide+ELU.
// ---------------------------------------------------------------------------
__global__ __launch_bounds__(256) void gat_aggregate(
    const int* __restrict__ cnt, const unsigned int* __restrict__ arr,
    const float* __restrict__ s_src, const float* __restrict__ s_dst,
    const float* __restrict__ Wh, const int* __restrict__ of_cnt,
    const int2* __restrict__ of_list, float* __restrict__ out)
{
    __shared__ float acc[64 * 65];
    __shared__ float rsum[64];
    const int t = threadIdx.x;
    const int lane = t & 63;
    const int w = t >> 6;
    const int b = blockIdx.x;

    for (int i = t; i < 64 * 65; i += 256) acc[i] = 0.f;
    if (t < 64) rsum[t] = 0.f;
    __syncthreads();

    const float4* __restrict__ Wh4 = (const float4*)Wh;
    const int fq = lane & 15;

    for (int sub = w; sub < NSUB; sub += 4) {
        const int ci = b * NSUB + sub;
        const int c = min(cnt[ci], CAP);
        const unsigned int* __restrict__ ap = arr + (size_t)ci * CAP;
        for (int off = 0; off < c; off += 64) {
            const int m = min(c - off, 64);
            int sl = 0, dd = 0;
            float ee = 0.f;
            if (lane < m) {
                const unsigned int en = ap[off + lane];   // coalesced 4B
                sl = (int)(en >> 16);
                dd = (int)(en & 0xffffu);
                const float sc = s_src[b * 64 + sl] + s_dst[dd];
                ee = __expf(-(sc > 0.f ? sc : ALPHA * sc));
                atomicAdd(&rsum[sl], ee);
            }
            for (int t0 = 0; t0 < m; t0 += 4) {
                const int el = t0 + (lane >> 4);          // this group's edge
                const int   slt = __shfl(sl, el & 63);    // always a valid lane
                const int   ddt = __shfl(dd, el & 63);
                float       et  = __shfl(ee, el & 63);
                if (el >= m) et = 0.f;                    // tail pad contributes 0
                const float4 wv = Wh4[(size_t)ddt * 16 + fq];  // 256B/edge
                float* a0p = &acc[slt * 65 + fq * 4];
                atomicAdd(a0p + 0, et * wv.x);
                atomicAdd(a0p + 1, et * wv.y);
                atomicAdd(a0p + 2, et * wv.z);
                atomicAdd(a0p + 3, et * wv.w);
            }
        }
    }

    // Overflow path (normally of_cnt == 0; correctness backstop only)
    const int nof = of_cnt[0];
    for (int i = t; i < nof; i += 256) {
        const int2 e2 = of_list[i];
        if ((e2.x >> 6) == b) {
            const int sl = e2.x & 63;
            const float sc = s_src[e2.x] + s_dst[e2.y];
            const float ee = __expf(-(sc > 0.f ? sc : ALPHA * sc));
            atomicAdd(&rsum[sl], ee);
            for (int f = 0; f < 64; ++f)
                atomicAdd(&acc[sl * 65 + f], ee * Wh[(size_t)e2.y * F_OUT + f]);
        }
    }
    __syncthreads();

    #pragma unroll
    for (int r = 0; r < 16; ++r) {
        const int idx = r * 256 + t;       // 64 nodes x 64 feats
        const int n = idx >> 6, f = idx & 63;
        const int node = b * 64 + n;
        if (node < N_NODES) {
            float v = acc[n * 65 + f] / rsum[n];
            v = v > 0.f ? v : (__expf(v) - 1.f);
            out[(size_t)node * F_OUT + f] = v;   // coalesced
        }
    }
}

extern "C" void kernel_launch(void* const* d_in, const int* in_sizes, int n_in,
                              void* d_out, int out_size, void* d_ws, size_t ws_size,
                              hipStream_t stream) {
    const float* x    = (const float*)d_in[0];
    const int*   edge = (const int*)  d_in[1];
    const float* W    = (const float*)d_in[2];
    const float* a    = (const float*)d_in[3];
    float* out = (float*)d_out;

    float* ws = (float*)d_ws;
    float*        Wh      = ws;                                   // 3,200,000 f
    unsigned int* arr     = (unsigned int*)(Wh + (size_t)N_NODES * F_OUT); // 3,203,072 u
    float*        s_src   = (float*)(arr + (size_t)NB * NSUB * CAP);       // 50,000 f
    float*        s_dst   = s_src + N_NODES;                      // 50,000 f
    int*          cnt     = (int*)(s_dst + N_NODES);              // 6,256 i
    int2*         of_list = (int2*)(cnt + NB * NSUB);             // 8,192 int2 (8B-aligned)
    int*          of_cnt  = (int*)(of_list + OF_CAP);             // 1 i

    hipMemsetAsync(cnt, 0, (size_t)NB * NSUB * sizeof(int), stream);
    hipMemsetAsync(of_cnt, 0, sizeof(int), stream);

    gat_gemm<<<1280, 256, 0, stream>>>(x, W, a, Wh, s_src, s_dst);
    gat_bucket<<<N_EDGES / 256, 256, 0, stream>>>(edge, cnt, arr, of_cnt, of_list);
    gat_aggregate<<<NB, 256, 0, stream>>>(cnt, arr, s_src, s_dst, Wh,
                                          of_cnt, of_list, out);
}

// Round 6
// 381.124 us; speedup vs baseline: 2.5674x; 2.5674x over previous
//
#include <hip/hip_runtime.h>

#define N_NODES 50000
#define N_EDGES 1600000
#define F_IN 256
#define F_OUT 64
#define ALPHA 0.2f

#define BS 32                 // nodes per bucket
#define NB 1563               // ceil(50000/32)
#define NSUB 8                // sub-buckets keyed by blockIdx&7 (~XCD)
#define CAP 256               // per (sub,bucket) capacity; mean 128, sd 11
#define LDS_CAP 1536          // per-bucket LDS edge capacity; mean 1024, sd 32
#define OF_CAP 16384          // overflow list (normally empty)

// ---------------------------------------------------------------------------
// Kernel A: Wh = x @ W. W slice in REGISTERS (wave w owns K rows [64w,64w+64),
// col=lane -> 64 VGPRs). No ds_read in K loop. Cross-wave K-reduce via 8KB
// LDS. Fused s_src/s_dst epilogue. (Correctness-verified in R5.)
// ---------------------------------------------------------------------------
__global__ __launch_bounds__(256) void gat_gemm(
    const float* __restrict__ x, const float* __restrict__ W,
    const float* __restrict__ a, float* __restrict__ Wh,
    float* __restrict__ s_src, float* __restrict__ s_dst)
{
    __shared__ float part[4 * 512];
    const int t = threadIdx.x;
    const int lane = t & 63;
    const int w = t >> 6;

    float wreg[64];
    #pragma unroll
    for (int j = 0; j < 64; ++j)
        wreg[j] = W[(size_t)(w * 64 + j) * F_OUT + lane];

    const float a0 = a[lane];
    const float a1 = a[F_OUT + lane];

    for (int c = blockIdx.x; c < N_NODES / 8; c += gridDim.x) {
        const int node0 = c * 8;
        float accs[8];
        #pragma unroll
        for (int n = 0; n < 8; ++n) {
            const float4* __restrict__ xp =
                (const float4*)(x + (size_t)(node0 + n) * F_IN + w * 64);
            float accA = 0.f, accB = 0.f;
            #pragma unroll
            for (int j = 0; j < 16; ++j) {
                const float4 xk = xp[j];
                accA = fmaf(xk.x, wreg[4 * j + 0], accA);
                accB = fmaf(xk.y, wreg[4 * j + 1], accB);
                accA = fmaf(xk.z, wreg[4 * j + 2], accA);
                accB = fmaf(xk.w, wreg[4 * j + 3], accB);
            }
            accs[n] = accA + accB;
        }
        __syncthreads();
        #pragma unroll
        for (int n = 0; n < 8; ++n)
            part[w * 512 + n * 64 + lane] = accs[n];
        __syncthreads();
        #pragma unroll
        for (int r = 0; r < 2; ++r) {
            const int idx = r * 256 + t;
            const int n = idx >> 6;
            const float v = part[idx] + part[512 + idx] +
                            part[1024 + idx] + part[1536 + idx];
            Wh[(size_t)(node0 + n) * F_OUT + lane] = v;
            float p = v * a0, q = v * a1;
            #pragma unroll
            for (int off = 32; off > 0; off >>= 1) {
                p += __shfl_down(p, off);
                q += __shfl_down(q, off);
            }
            if (lane == 0) { s_src[node0 + n] = p; s_dst[node0 + n] = q; }
        }
    }
}

// ---------------------------------------------------------------------------
// Pass 1: bucket edges by src>>5 into sub-bucket blockIdx&7. SUB-MAJOR layout
// (cnt[sub][bucket], arr[sub][bucket][cap]) so each XCD's counters and tail
// lines are contiguous -> no cross-XCD line ping-pong. 4B packed entries.
// ---------------------------------------------------------------------------
__global__ __launch_bounds__(256) void gat_bucket(
    const int* __restrict__ edge, int* __restrict__ cnt,
    unsigned int* __restrict__ arr, int* __restrict__ of_cnt,
    int2* __restrict__ of_list)
{
    const int e = blockIdx.x * 256 + threadIdx.x;   // grid exactly covers E
    const int s = edge[e];
    const int d = edge[N_EDGES + e];
    const int ci = (blockIdx.x & 7) * NB + (s >> 5);
    const int pos = atomicAdd(&cnt[ci], 1);
    if (pos < CAP) {
        arr[(size_t)ci * CAP + pos] = ((unsigned)(s & 31) << 16) | (unsigned)d;
    } else {
        const int op = atomicAdd(of_cnt, 1);
        if (op < OF_CAP) of_list[op] = make_int2(s, d);
    }
}

// ---------------------------------------------------------------------------
// Pass 2: block per 32-node bucket. LDS counting sort of ~1024 edges by
// src-local (int hist -> scan -> scatter, ee computed once at scatter into
// packed uint2{dst, ee}). Then wave-per-node register accumulation:
// per edge 1 ds_read_b64 broadcast + 1 coalesced 256B Wh gather + 1 fma.
// rowsum is wave-uniform. No atomics in the hot loop, no global scatter.
// ---------------------------------------------------------------------------
__global__ __launch_bounds__(256) void gat_aggregate(
    const int* __restrict__ cnt, const unsigned int* __restrict__ arr,
    const float* __restrict__ s_src, const float* __restrict__ s_dst,
    const float* __restrict__ Wh, const int* __restrict__ of_cnt,
    const int2* __restrict__ of_list, float* __restrict__ out)
{
    __shared__ uint2 ent2[LDS_CAP];      // {dst, ee bits}
    __shared__ int   bin[BS];            // hist -> cursor
    __shared__ int   start[BS + 1];
    __shared__ int   Pl[NSUB + 1];
    const int t = threadIdx.x;
    const int lane = t & 63;
    const int w = t >> 6;
    const int b = blockIdx.x;

    if (t < BS) bin[t] = 0;
    if (t == 0) {
        int run = 0;
        #pragma unroll
        for (int s2 = 0; s2 < NSUB; ++s2) {
            Pl[s2] = run;
            run += min(cnt[s2 * NB + b], CAP);
        }
        Pl[NSUB] = run;
    }
    __syncthreads();
    const int C = Pl[NSUB];             // <= 2048
    const int nof = min(of_cnt[0], OF_CAP);

    // ---- hist (stash entries in registers; <=8 per thread since C<=2048)
    unsigned enr[8];
    int nr = 0;
    for (int g = t; g < C; g += 256) {
        int sub = 0;
        #pragma unroll
        for (int s2 = 1; s2 < NSUB; ++s2) sub += (g >= Pl[s2]);
        const unsigned en = arr[((size_t)(sub * NB + b)) * CAP + (g - Pl[sub])];
        enr[nr++] = en;
        atomicAdd(&bin[en >> 16], 1);
    }
    for (int i = t; i < nof; i += 256) {
        const int2 e2 = of_list[i];
        if ((e2.x >> 5) == b) atomicAdd(&bin[e2.x & 31], 1);
    }
    __syncthreads();
    if (t == 0) {
        int run = 0;
        #pragma unroll
        for (int n = 0; n < BS; ++n) {
            start[n] = run;
            run += bin[n];
            bin[n] = start[n];          // becomes cursor
        }
        start[BS] = run;
    }
    __syncthreads();

    // ---- sort-scatter + ee compute (one exp per edge)
    for (int r = 0; r < nr; ++r) {
        const unsigned en = enr[r];
        const int sl = (int)(en >> 16);
        const int d  = (int)(en & 0xffffu);
        const float sc = s_src[b * BS + sl] + s_dst[d];
        const float ee = __expf(-(sc > 0.f ? sc : ALPHA * sc));
        const int pos = atomicAdd(&bin[sl], 1);
        if (pos < LDS_CAP) ent2[pos] = make_uint2((unsigned)d, __float_as_uint(ee));
    }
    for (int i = t; i < nof; i += 256) {
        const int2 e2 = of_list[i];
        if ((e2.x >> 5) == b) {
            const float sc = s_src[e2.x] + s_dst[e2.y];
            const float ee = __expf(-(sc > 0.f ? sc : ALPHA * sc));
            const int pos = atomicAdd(&bin[e2.x & 31], 1);
            if (pos < LDS_CAP) ent2[pos] = make_uint2((unsigned)e2.y, __float_as_uint(ee));
        }
    }
    __syncthreads();

    // ---- aggregate: wave w handles nodes [8w, 8w+8), lane = feature
    for (int n = w * 8; n < w * 8 + 8; ++n) {
        const int node = b * BS + n;
        if (node >= N_NODES) break;
        const int r0 = start[n];
        const int r1 = min(start[n + 1], LDS_CAP);
        float acc = 0.f, rsum = 0.f;
        for (int j = r0; j < r1; ++j) {
            const uint2 en = ent2[j];                       // ds_read_b64 broadcast
            const float ee = __uint_as_float(en.y);
            acc = fmaf(ee, Wh[(size_t)en.x * F_OUT + lane], acc);  // 256B coalesced
            rsum += ee;
        }
        float v = acc / rsum;
        v = v > 0.f ? v : (__expf(v) - 1.f);
        out[(size_t)node * F_OUT + lane] = v;               // coalesced
    }
}

extern "C" void kernel_launch(void* const* d_in, const int* in_sizes, int n_in,
                              void* d_out, int out_size, void* d_ws, size_t ws_size,
                              hipStream_t stream) {
    const float* x    = (const float*)d_in[0];
    const int*   edge = (const int*)  d_in[1];
    const float* W    = (const float*)d_in[2];
    const float* a    = (const float*)d_in[3];
    float* out = (float*)d_out;

    float* ws = (float*)d_ws;
    float*        Wh      = ws;                                       // 3,200,000 f
    unsigned int* arr     = (unsigned int*)(Wh + (size_t)N_NODES * F_OUT);
    float*        s_src   = (float*)(arr + (size_t)NSUB * NB * CAP);  // 50,000 f
    float*        s_dst   = s_src + N_NODES;                          // 50,000 f
    int*          cnt     = (int*)(s_dst + N_NODES);                  // 12,504 i
    int2*         of_list = (int2*)(cnt + NSUB * NB);                 // 8B-aligned
    int*          of_cnt  = (int*)(of_list + OF_CAP);

    hipMemsetAsync(cnt, 0, (size_t)NSUB * NB * sizeof(int), stream);
    hipMemsetAsync(of_cnt, 0, sizeof(int), stream);

    gat_gemm<<<1280, 256, 0, stream>>>(x, W, a, Wh, s_src, s_dst);
    gat_bucket<<<N_EDGES / 256, 256, 0, stream>>>(edge, cnt, arr, of_cnt, of_list);
    gat_aggregate<<<NB, 256, 0, stream>>>(cnt, arr, s_src, s_dst, Wh,
                                          of_cnt, of_list, out);
}

// Round 7
// 342.518 us; speedup vs baseline: 2.8568x; 1.1127x over previous
//
#include <hip/hip_runtime.h>

#define N_NODES 50000
#define N_EDGES 1600000
#define F_IN 256
#define F_OUT 64
#define ALPHA 0.2f

#define CH 16                 // nodes per gemm chunk
#define BS 32                 // nodes per bucket
#define NB 1563               // ceil(50000/32)
#define NSUB 8                // sub-buckets keyed by blockIdx&7 (~XCD)
#define CAP 256               // per (sub,bucket) capacity; mean 128, sd 11
#define LDS_CAP 1536          // per-bucket LDS edge capacity; mean 1024, sd 32
#define OF_CAP 16384          // overflow list (normally empty)

// ---------------------------------------------------------------------------
// Kernel A: Wh = x @ W. x-tile (16 nodes x 256 K = 16KB) staged in LDS with
// COALESCED float4 loads (the R5/R6 versions used wave-uniform broadcast
// global loads -- 16B/instr, latency-bound at 19% VALUBusy). W slice in
// registers (wave w owns K rows [64w,64w+64), col=lane). Compute reads x
// from LDS via broadcast ds_read_b128 (~120cyc vs ~400 global). Cross-wave
// K-reduce via 16KB LDS. Fused s_src/s_dst epilogue.
// ---------------------------------------------------------------------------
__global__ __launch_bounds__(256) void gat_gemm(
    const float* __restrict__ x, const float* __restrict__ W,
    const float* __restrict__ a, float* __restrict__ Wh,
    float* __restrict__ s_src, float* __restrict__ s_dst)
{
    __shared__ float xs[CH * F_IN];          // 16 KB
    __shared__ float part[4 * CH * F_OUT];   // 16 KB
    const int t = threadIdx.x;
    const int lane = t & 63;
    const int w = t >> 6;

    float wreg[64];
    #pragma unroll
    for (int j = 0; j < 64; ++j)
        wreg[j] = W[(size_t)(w * 64 + j) * F_OUT + lane];   // coalesced, once

    const float a0 = a[lane];
    const float a1 = a[F_OUT + lane];

    for (int c = blockIdx.x; c < N_NODES / CH; c += gridDim.x) {
        const int node0 = c * CH;
        __syncthreads();   // WAR: xs/part from previous chunk
        {
            const float4* __restrict__ xg = (const float4*)(x + (size_t)node0 * F_IN);
            float4* xsv = (float4*)xs;
            #pragma unroll
            for (int i = 0; i < 4; ++i)
                xsv[t + i * 256] = xg[t + i * 256];   // coalesced 1KB/wave/instr
        }
        __syncthreads();

        #pragma unroll 2
        for (int n = 0; n < CH; ++n) {
            const float4* __restrict__ xp = (const float4*)(xs + n * F_IN + w * 64);
            float accA = 0.f, accB = 0.f;
            #pragma unroll
            for (int j = 0; j < 16; ++j) {
                const float4 xk = xp[j];              // ds_read_b128 broadcast
                accA = fmaf(xk.x, wreg[4 * j + 0], accA);
                accB = fmaf(xk.y, wreg[4 * j + 1], accB);
                accA = fmaf(xk.z, wreg[4 * j + 2], accA);
                accB = fmaf(xk.w, wreg[4 * j + 3], accB);
            }
            part[(w * CH + n) * 64 + lane] = accA + accB;
        }
        __syncthreads();

        #pragma unroll
        for (int r = 0; r < CH / 4; ++r) {
            const int idx = r * 256 + t;              // node = r*4 + w, feat = lane
            const int n = idx >> 6;
            const float v = part[idx] + part[CH * 64 + idx] +
                            part[2 * CH * 64 + idx] + part[3 * CH * 64 + idx];
            Wh[(size_t)(node0 + n) * F_OUT + lane] = v;
            float p = v * a0, q = v * a1;
            #pragma unroll
            for (int off = 32; off > 0; off >>= 1) {
                p += __shfl_down(p, off);
                q += __shfl_down(q, off);
            }
            if (lane == 0) { s_src[node0 + n] = p; s_dst[node0 + n] = q; }
        }
    }
}

// ---------------------------------------------------------------------------
// Pass 1: bucket edges by src>>5 into sub-bucket blockIdx&7. SUB-MAJOR layout
// (cnt[sub][bucket], arr[sub][bucket][cap]) so each XCD's counters and tail
// lines are contiguous -> no cross-XCD line ping-pong. 4B packed entries.
// (Unchanged from R6.)
// ---------------------------------------------------------------------------
__global__ __launch_bounds__(256) void gat_bucket(
    const int* __restrict__ edge, int* __restrict__ cnt,
    unsigned int* __restrict__ arr, int* __restrict__ of_cnt,
    int2* __restrict__ of_list)
{
    const int e = blockIdx.x * 256 + threadIdx.x;   // grid exactly covers E
    const int s = edge[e];
    const int d = edge[N_EDGES + e];
    const int ci = (blockIdx.x & 7) * NB + (s >> 5);
    const int pos = atomicAdd(&cnt[ci], 1);
    if (pos < CAP) {
        arr[(size_t)ci * CAP + pos] = ((unsigned)(s & 31) << 16) | (unsigned)d;
    } else {
        const int op = atomicAdd(of_cnt, 1);
        if (op < OF_CAP) of_list[op] = make_int2(s, d);
    }
}

// ---------------------------------------------------------------------------
// Pass 2: block per 32-node bucket. LDS counting sort of ~1024 edges by
// src-local, ee computed once at scatter into packed uint2{dst, ee}. Then
// wave-per-node register accumulation: per edge 1 ds_read_b64 broadcast +
// 1 coalesced 256B Wh gather + 1 fma. No atomics in the hot loop.
// (Unchanged from R6.)
// ---------------------------------------------------------------------------
__global__ __launch_bounds__(256) void gat_aggregate(
    const int* __restrict__ cnt, const unsigned int* __restrict__ arr,
    const float* __restrict__ s_src, const float* __restrict__ s_dst,
    const float* __restrict__ Wh, const int* __restrict__ of_cnt,
    const int2* __restrict__ of_list, float* __restrict__ out)
{
    __shared__ uint2 ent2[LDS_CAP];      // {dst, ee bits}
    __shared__ int   bin[BS];            // hist -> cursor
    __shared__ int   start[BS + 1];
    __shared__ int   Pl[NSUB + 1];
    const int t = threadIdx.x;
    const int lane = t & 63;
    const int w = t >> 6;
    const int b = blockIdx.x;

    if (t < BS) bin[t] = 0;
    if (t == 0) {
        int run = 0;
        #pragma unroll
        for (int s2 = 0; s2 < NSUB; ++s2) {
            Pl[s2] = run;
            run += min(cnt[s2 * NB + b], CAP);
        }
        Pl[NSUB] = run;
    }
    __syncthreads();
    const int C = Pl[NSUB];             // <= 2048
    const int nof = min(of_cnt[0], OF_CAP);

    // ---- hist (stash entries in registers; <=8 per thread since C<=2048)
    unsigned enr[8];
    int nr = 0;
    for (int g = t; g < C; g += 256) {
        int sub = 0;
        #pragma unroll
        for (int s2 = 1; s2 < NSUB; ++s2) sub += (g >= Pl[s2]);
        const unsigned en = arr[((size_t)(sub * NB + b)) * CAP + (g - Pl[sub])];
        enr[nr++] = en;
        atomicAdd(&bin[en >> 16], 1);
    }
    for (int i = t; i < nof; i += 256) {
        const int2 e2 = of_list[i];
        if ((e2.x >> 5) == b) atomicAdd(&bin[e2.x & 31], 1);
    }
    __syncthreads();
    if (t == 0) {
        int run = 0;
        #pragma unroll
        for (int n = 0; n < BS; ++n) {
            start[n] = run;
            run += bin[n];
            bin[n] = start[n];          // becomes cursor
        }
        start[BS] = run;
    }
    __syncthreads();

    // ---- sort-scatter + ee compute (one exp per edge)
    for (int r = 0; r < nr; ++r) {
        const unsigned en = enr[r];
        const int sl = (int)(en >> 16);
        const int d  = (int)(en & 0xffffu);
        const float sc = s_src[b * BS + sl] + s_dst[d];
        const float ee = __expf(-(sc > 0.f ? sc : ALPHA * sc));
        const int pos = atomicAdd(&bin[sl], 1);
        if (pos < LDS_CAP) ent2[pos] = make_uint2((unsigned)d, __float_as_uint(ee));
    }
    for (int i = t; i < nof; i += 256) {
        const int2 e2 = of_list[i];
        if ((e2.x >> 5) == b) {
            const float sc = s_src[e2.x] + s_dst[e2.y];
            const float ee = __expf(-(sc > 0.f ? sc : ALPHA * sc));
            const int pos = atomicAdd(&bin[e2.x & 31], 1);
            if (pos < LDS_CAP) ent2[pos] = make_uint2((unsigned)e2.y, __float_as_uint(ee));
        }
    }
    __syncthreads();

    // ---- aggregate: wave w handles nodes [8w, 8w+8), lane = feature
    for (int n = w * 8; n < w * 8 + 8; ++n) {
        const int node = b * BS + n;
        if (node >= N_NODES) break;
        const int r0 = start[n];
        const int r1 = min(start[n + 1], LDS_CAP);
        float acc = 0.f, rsum = 0.f;
        for (int j = r0; j < r1; ++j) {
            const uint2 en = ent2[j];                       // ds_read_b64 broadcast
            const float ee = __uint_as_float(en.y);
            acc = fmaf(ee, Wh[(size_t)en.x * F_OUT + lane], acc);  // 256B coalesced
            rsum += ee;
        }
        float v = acc / rsum;
        v = v > 0.f ? v : (__expf(v) - 1.f);
        out[(size_t)node * F_OUT + lane] = v;               // coalesced
    }
}

extern "C" void kernel_launch(void* const* d_in, const int* in_sizes, int n_in,
                              void* d_out, int out_size, void* d_ws, size_t ws_size,
                              hipStream_t stream) {
    const float* x    = (const float*)d_in[0];
    const int*   edge = (const int*)  d_in[1];
    const float* W    = (const float*)d_in[2];
    const float* a    = (const float*)d_in[3];
    float* out = (float*)d_out;

    float* ws = (float*)d_ws;
    float*        Wh      = ws;                                       // 3,200,000 f
    unsigned int* arr     = (unsigned int*)(Wh + (size_t)N_NODES * F_OUT);
    float*        s_src   = (float*)(arr + (size_t)NSUB * NB * CAP);  // 50,000 f
    float*        s_dst   = s_src + N_NODES;                          // 50,000 f
    int*          cnt     = (int*)(s_dst + N_NODES);                  // 12,504 i
    int2*         of_list = (int2*)(cnt + NSUB * NB);                 // 8B-aligned
    int*          of_cnt  = (int*)(of_list + OF_CAP);

    hipMemsetAsync(cnt, 0, (size_t)NSUB * NB * sizeof(int), stream);
    hipMemsetAsync(of_cnt, 0, sizeof(int), stream);

    gat_gemm<<<1563, 256, 0, stream>>>(x, W, a, Wh, s_src, s_dst);
    gat_bucket<<<N_EDGES / 256, 256, 0, stream>>>(edge, cnt, arr, of_cnt, of_list);
    gat_aggregate<<<NB, 256, 0, stream>>>(cnt, arr, s_src, s_dst, Wh,
                                          of_cnt, of_list, out);
}

// Round 8
// 285.874 us; speedup vs baseline: 3.4228x; 1.1981x over previous
//
#include <hip/hip_runtime.h>

#define N_NODES 50000
#define N_EDGES 1600000
#define F_IN 256
#define F_OUT 64
#define ALPHA 0.2f

#define CH 16                 // nodes per gemm chunk
#define BS 32                 // nodes per bucket
#define NB 1563               // ceil(50000/32)
#define NSUB 8                // sub-buckets keyed by blockIdx&7 (~XCD)
#define CAP 256               // per (sub,bucket) capacity; mean 128, sd 11
#define LDS_CAP 1536          // per-bucket LDS edge capacity; mean 1024, sd 32
#define OF_CAP 16384          // overflow list (normally empty)

// ---------------------------------------------------------------------------
// Kernel A: Wh = x @ W. x-tile staged in LDS with coalesced float4 loads,
// W slice in registers, cross-wave K-reduce via LDS. (Unchanged from R7.)
// ---------------------------------------------------------------------------
__global__ __launch_bounds__(256) void gat_gemm(
    const float* __restrict__ x, const float* __restrict__ W,
    const float* __restrict__ a, float* __restrict__ Wh,
    float* __restrict__ s_src, float* __restrict__ s_dst)
{
    __shared__ float xs[CH * F_IN];          // 16 KB
    __shared__ float part[4 * CH * F_OUT];   // 16 KB
    const int t = threadIdx.x;
    const int lane = t & 63;
    const int w = t >> 6;

    float wreg[64];
    #pragma unroll
    for (int j = 0; j < 64; ++j)
        wreg[j] = W[(size_t)(w * 64 + j) * F_OUT + lane];

    const float a0 = a[lane];
    const float a1 = a[F_OUT + lane];

    for (int c = blockIdx.x; c < N_NODES / CH; c += gridDim.x) {
        const int node0 = c * CH;
        __syncthreads();
        {
            const float4* __restrict__ xg = (const float4*)(x + (size_t)node0 * F_IN);
            float4* xsv = (float4*)xs;
            #pragma unroll
            for (int i = 0; i < 4; ++i)
                xsv[t + i * 256] = xg[t + i * 256];
        }
        __syncthreads();

        #pragma unroll 2
        for (int n = 0; n < CH; ++n) {
            const float4* __restrict__ xp = (const float4*)(xs + n * F_IN + w * 64);
            float accA = 0.f, accB = 0.f;
            #pragma unroll
            for (int j = 0; j < 16; ++j) {
                const float4 xk = xp[j];
                accA = fmaf(xk.x, wreg[4 * j + 0], accA);
                accB = fmaf(xk.y, wreg[4 * j + 1], accB);
                accA = fmaf(xk.z, wreg[4 * j + 2], accA);
                accB = fmaf(xk.w, wreg[4 * j + 3], accB);
            }
            part[(w * CH + n) * 64 + lane] = accA + accB;
        }
        __syncthreads();

        #pragma unroll
        for (int r = 0; r < CH / 4; ++r) {
            const int idx = r * 256 + t;
            const int n = idx >> 6;
            const float v = part[idx] + part[CH * 64 + idx] +
                            part[2 * CH * 64 + idx] + part[3 * CH * 64 + idx];
            Wh[(size_t)(node0 + n) * F_OUT + lane] = v;
            float p = v * a0, q = v * a1;
            #pragma unroll
            for (int off = 32; off > 0; off >>= 1) {
                p += __shfl_down(p, off);
                q += __shfl_down(q, off);
            }
            if (lane == 0) { s_src[node0 + n] = p; s_dst[node0 + n] = q; }
        }
    }
}

// ---------------------------------------------------------------------------
// Pass 1: bucket edges by src>>5 into sub-bucket blockIdx&7, sub-major
// layout. (Unchanged from R6/R7.)
// ---------------------------------------------------------------------------
__global__ __launch_bounds__(256) void gat_bucket(
    const int* __restrict__ edge, int* __restrict__ cnt,
    unsigned int* __restrict__ arr, int* __restrict__ of_cnt,
    int2* __restrict__ of_list)
{
    const int e = blockIdx.x * 256 + threadIdx.x;
    const int s = edge[e];
    const int d = edge[N_EDGES + e];
    const int ci = (blockIdx.x & 7) * NB + (s >> 5);
    const int pos = atomicAdd(&cnt[ci], 1);
    if (pos < CAP) {
        arr[(size_t)ci * CAP + pos] = ((unsigned)(s & 31) << 16) | (unsigned)d;
    } else {
        const int op = atomicAdd(of_cnt, 1);
        if (op < OF_CAP) of_list[op] = make_int2(s, d);
    }
}

// ---------------------------------------------------------------------------
// Pass 2: block per 32-node bucket. LDS counting sort (unchanged), then
// QUARTER-WAVE x FLOAT4 aggregation: lane = (quarter q, feat-quad fq);
// each iteration handles 8 edges via 2 broadcast ds_read_b64 + 2
// global_load_dwordx4 in flight -> 4x fewer VMEM instrs and 8 edges of
// latency overlap (R7 was one dependent 4B-gather chain per edge, 22%
// VALUBusy latency-bound). Cross-quarter shfl_xor reduce at node end.
// ---------------------------------------------------------------------------
__global__ __launch_bounds__(256) void gat_aggregate(
    const int* __restrict__ cnt, const unsigned int* __restrict__ arr,
    const float* __restrict__ s_src, const float* __restrict__ s_dst,
    const float* __restrict__ Wh, const int* __restrict__ of_cnt,
    const int2* __restrict__ of_list, float* __restrict__ out)
{
    __shared__ uint2 ent2[LDS_CAP];      // {dst, ee bits}
    __shared__ int   bin[BS];            // hist -> cursor
    __shared__ int   start[BS + 1];
    __shared__ int   Pl[NSUB + 1];
    const int t = threadIdx.x;
    const int lane = t & 63;
    const int w = t >> 6;
    const int b = blockIdx.x;

    if (t < BS) bin[t] = 0;
    if (t == 0) {
        int run = 0;
        #pragma unroll
        for (int s2 = 0; s2 < NSUB; ++s2) {
            Pl[s2] = run;
            run += min(cnt[s2 * NB + b], CAP);
        }
        Pl[NSUB] = run;
    }
    __syncthreads();
    const int C = Pl[NSUB];             // <= 2048
    const int nof = min(of_cnt[0], OF_CAP);

    // ---- hist (stash entries in registers; <=8 per thread since C<=2048)
    unsigned enr[8];
    int nr = 0;
    for (int g = t; g < C; g += 256) {
        int sub = 0;
        #pragma unroll
        for (int s2 = 1; s2 < NSUB; ++s2) sub += (g >= Pl[s2]);
        const unsigned en = arr[((size_t)(sub * NB + b)) * CAP + (g - Pl[sub])];
        enr[nr++] = en;
        atomicAdd(&bin[en >> 16], 1);
    }
    for (int i = t; i < nof; i += 256) {
        const int2 e2 = of_list[i];
        if ((e2.x >> 5) == b) atomicAdd(&bin[e2.x & 31], 1);
    }
    __syncthreads();
    if (t == 0) {
        int run = 0;
        #pragma unroll
        for (int n = 0; n < BS; ++n) {
            start[n] = run;
            run += bin[n];
            bin[n] = start[n];          // becomes cursor
        }
        start[BS] = run;
    }
    __syncthreads();

    // ---- sort-scatter + ee compute (one exp per edge)
    for (int r = 0; r < nr; ++r) {
        const unsigned en = enr[r];
        const int sl = (int)(en >> 16);
        const int d  = (int)(en & 0xffffu);
        const float sc = s_src[b * BS + sl] + s_dst[d];
        const float ee = __expf(-(sc > 0.f ? sc : ALPHA * sc));
        const int pos = atomicAdd(&bin[sl], 1);
        if (pos < LDS_CAP) ent2[pos] = make_uint2((unsigned)d, __float_as_uint(ee));
    }
    for (int i = t; i < nof; i += 256) {
        const int2 e2 = of_list[i];
        if ((e2.x >> 5) == b) {
            const float sc = s_src[e2.x] + s_dst[e2.y];
            const float ee = __expf(-(sc > 0.f ? sc : ALPHA * sc));
            const int pos = atomicAdd(&bin[e2.x & 31], 1);
            if (pos < LDS_CAP) ent2[pos] = make_uint2((unsigned)e2.y, __float_as_uint(ee));
        }
    }
    __syncthreads();

    // ---- aggregate: wave w handles nodes [8w, 8w+8)
    const int q  = lane >> 4;          // quarter index: which edge in group
    const int fq = lane & 15;          // feature quad: feats [4fq, 4fq+4)
    const float4* __restrict__ Wh4 = (const float4*)Wh;

    for (int n = w * 8; n < w * 8 + 8; ++n) {
        const int node = b * BS + n;
        if (node >= N_NODES) break;
        const int r0 = start[n];
        const int r1 = min(start[n + 1], LDS_CAP);
        float4 acc = make_float4(0.f, 0.f, 0.f, 0.f);
        float rsum = 0.f;
        for (int j = r0; j < r1; j += 8) {
            const int ja = j + q;
            const int jb = j + 4 + q;
            const uint2 ea = ent2[min(ja, r1 - 1)];   // 4-addr broadcast ds_read_b64
            const uint2 eb = ent2[min(jb, r1 - 1)];
            const float eta = (ja < r1) ? __uint_as_float(ea.y) : 0.f;
            const float etb = (jb < r1) ? __uint_as_float(eb.y) : 0.f;
            const float4 wa = Wh4[(size_t)ea.x * 16 + fq];   // dwordx4, 2 in flight
            const float4 wb = Wh4[(size_t)eb.x * 16 + fq];
            acc.x = fmaf(eta, wa.x, acc.x);
            acc.y = fmaf(eta, wa.y, acc.y);
            acc.z = fmaf(eta, wa.z, acc.z);
            acc.w = fmaf(eta, wa.w, acc.w);
            acc.x = fmaf(etb, wb.x, acc.x);
            acc.y = fmaf(etb, wb.y, acc.y);
            acc.z = fmaf(etb, wb.z, acc.z);
            acc.w = fmaf(etb, wb.w, acc.w);
            rsum += eta + etb;
        }
        // cross-quarter reduction (q is lane>>4; xor 16 then 32 merges quarters)
        acc.x += __shfl_xor(acc.x, 16); acc.x += __shfl_xor(acc.x, 32);
        acc.y += __shfl_xor(acc.y, 16); acc.y += __shfl_xor(acc.y, 32);
        acc.z += __shfl_xor(acc.z, 16); acc.z += __shfl_xor(acc.z, 32);
        acc.w += __shfl_xor(acc.w, 16); acc.w += __shfl_xor(acc.w, 32);
        rsum  += __shfl_xor(rsum, 16);  rsum  += __shfl_xor(rsum, 32);

        float4 v;
        v.x = acc.x / rsum; v.y = acc.y / rsum;
        v.z = acc.z / rsum; v.w = acc.w / rsum;
        v.x = v.x > 0.f ? v.x : (__expf(v.x) - 1.f);
        v.y = v.y > 0.f ? v.y : (__expf(v.y) - 1.f);
        v.z = v.z > 0.f ? v.z : (__expf(v.z) - 1.f);
        v.w = v.w > 0.f ? v.w : (__expf(v.w) - 1.f);
        if (q == 0)
            ((float4*)out)[(size_t)node * 16 + fq] = v;   // quarter-wave 256B store
    }
}

extern "C" void kernel_launch(void* const* d_in, const int* in_sizes, int n_in,
                              void* d_out, int out_size, void* d_ws, size_t ws_size,
                              hipStream_t stream) {
    const float* x    = (const float*)d_in[0];
    const int*   edge = (const int*)  d_in[1];
    const float* W    = (const float*)d_in[2];
    const float* a    = (const float*)d_in[3];
    float* out = (float*)d_out;

    float* ws = (float*)d_ws;
    float*        Wh      = ws;                                       // 3,200,000 f
    unsigned int* arr     = (unsigned int*)(Wh + (size_t)N_NODES * F_OUT);
    float*        s_src   = (float*)(arr + (size_t)NSUB * NB * CAP);  // 50,000 f
    float*        s_dst   = s_src + N_NODES;                          // 50,000 f
    int*          cnt     = (int*)(s_dst + N_NODES);                  // 12,504 i
    int2*         of_list = (int2*)(cnt + NSUB * NB);                 // 8B-aligned
    int*          of_cnt  = (int*)(of_list + OF_CAP);

    hipMemsetAsync(cnt, 0, (size_t)NSUB * NB * sizeof(int), stream);
    hipMemsetAsync(of_cnt, 0, sizeof(int), stream);

    gat_gemm<<<1563, 256, 0, stream>>>(x, W, a, Wh, s_src, s_dst);
    gat_bucket<<<N_EDGES / 256, 256, 0, stream>>>(edge, cnt, arr, of_cnt, of_list);
    gat_aggregate<<<NB, 256, 0, stream>>>(cnt, arr, s_src, s_dst, Wh,
                                          of_cnt, of_list, out);
}

// Round 9
// 196.546 us; speedup vs baseline: 4.9785x; 1.4545x over previous
//
#include <hip/hip_runtime.h>

#define N_NODES 50000
#define N_EDGES 1600000
#define F_IN 256
#define F_OUT 64
#define ALPHA 0.2f

#define BS 64                 // nodes per bucket
#define NBK 782               // ceil(50000/64)
#define NSUB 8                // sub-buckets keyed by blockIdx&7
#define CAP 384               // per (sub,bucket) capacity; mean 256, sd ~15
#define EB 4096               // edges per bucket-sort block
#define NBB 391               // ceil(E/EB)
#define LDS_CAP 2560          // per-bucket LDS edge cap; mean 2048, sd ~45
#define OF_CAP 16384          // overflow list (normally empty)

typedef __attribute__((ext_vector_type(8))) short bf16x8;
typedef __attribute__((ext_vector_type(4))) float f32x4;

__device__ inline unsigned short f2bf(float f) {   // RNE fp32->bf16
    unsigned int u = __float_as_uint(f);
    return (unsigned short)((u + 0x7FFFu + ((u >> 16) & 1u)) >> 16);
}
__device__ inline float bf2f(unsigned short b) {
    return __uint_as_float(((unsigned int)b) << 16);
}

// ---------------------------------------------------------------------------
// W prepack (1 block, once): W fp32 -> bf16 in MFMA B-frag order:
// frag (ks,nt), lane l, elem j holds W[ks*32 + (l>>4)*8 + j][nt*16 + (l&15)].
// Dest-indexed so the 2B stores are coalesced.
// ---------------------------------------------------------------------------
__global__ __launch_bounds__(256) void gat_wprep(
    const float* __restrict__ W, unsigned short* __restrict__ Wf)
{
    for (int di = threadIdx.x; di < F_IN * F_OUT; di += 256) {
        const int j    = di & 7;
        const int lane = (di >> 3) & 63;
        const int tile = di >> 9;           // ks*4 + nt
        const int ks   = tile >> 2;
        const int nt   = tile & 3;
        const int k = ks * 32 + (lane >> 4) * 8 + j;
        const int n = nt * 16 + (lane & 15);
        Wf[di] = f2bf(W[k * F_OUT + n]);
    }
}

// ---------------------------------------------------------------------------
// Kernel A: Wh = x @ W via bf16 MFMA 16x16x32, 2-term precision split
// (x = hi + lo, both multiplied by W_hi): error ~0.003 << 0.117 threshold.
// Wave = one 16-node M-tile; block = 64 nodes; W frags staged in 32KB LDS.
// All 16 A-loads (dwordx4) issued up-front for deep VMEM pipelining.
// Epilogue: C-layout (row=(l>>4)*4+reg, col=l&15) store + s_src/s_dst dots.
// ---------------------------------------------------------------------------
__global__ __launch_bounds__(256) void gat_gemm(
    const float* __restrict__ x, const unsigned short* __restrict__ Wf,
    const float* __restrict__ a, float* __restrict__ Wh,
    float* __restrict__ s_src, float* __restrict__ s_dst)
{
    __shared__ unsigned short Wl[F_IN * F_OUT];   // 32 KB, frag-ordered bf16
    const int t = threadIdx.x;
    {
        const float4* __restrict__ src = (const float4*)Wf;
        float4* dst = (float4*)Wl;
        #pragma unroll
        for (int i = 0; i < 8; ++i) dst[t + i * 256] = src[t + i * 256];
    }
    __syncthreads();

    const int lane = t & 63;
    const int w    = t >> 6;
    const int q    = lane >> 4;
    const int c16  = lane & 15;
    const bf16x8* __restrict__ Wfrag = (const bf16x8*)Wl;  // [(ks*4+nt)*64+lane]

    float av[4], av2[4];
    #pragma unroll
    for (int nt = 0; nt < 4; ++nt) {
        av[nt]  = a[nt * 16 + c16];
        av2[nt] = a[F_OUT + nt * 16 + c16];
    }

    for (int c = blockIdx.x; c < NBK; c += gridDim.x) {
        const int node0 = c * 64 + w * 16;
        int row = node0 + c16;                   // A m-index = lane&15
        if (row >= N_NODES) row = N_NODES - 1;   // clamp; ghost stores guarded
        const float4* __restrict__ xp = (const float4*)(x + (size_t)row * F_IN);

        float4 xv[16];
        #pragma unroll
        for (int ks = 0; ks < 8; ++ks) {         // k = ks*32 + q*8 + j
            xv[2 * ks]     = xp[ks * 8 + q * 2];
            xv[2 * ks + 1] = xp[ks * 8 + q * 2 + 1];
        }

        f32x4 acc[4];
        #pragma unroll
        for (int nt = 0; nt < 4; ++nt) acc[nt] = (f32x4){0.f, 0.f, 0.f, 0.f};

        #pragma unroll
        for (int ks = 0; ks < 8; ++ks) {
            float xf[8] = {xv[2*ks].x,   xv[2*ks].y,   xv[2*ks].z,   xv[2*ks].w,
                           xv[2*ks+1].x, xv[2*ks+1].y, xv[2*ks+1].z, xv[2*ks+1].w};
            bf16x8 ah, al;
            #pragma unroll
            for (int j = 0; j < 8; ++j) {
                const unsigned short h = f2bf(xf[j]);
                ah[j] = (short)h;
                al[j] = (short)f2bf(xf[j] - bf2f(h));
            }
            #pragma unroll
            for (int nt = 0; nt < 4; ++nt) {
                const bf16x8 bh = Wfrag[(ks * 4 + nt) * 64 + lane];
                acc[nt] = __builtin_amdgcn_mfma_f32_16x16x32_bf16(ah, bh, acc[nt], 0, 0, 0);
                acc[nt] = __builtin_amdgcn_mfma_f32_16x16x32_bf16(al, bh, acc[nt], 0, 0, 0);
            }
        }

        #pragma unroll
        for (int r = 0; r < 4; ++r) {
            const int node = node0 + q * 4 + r;  // C row = (l>>4)*4 + reg
            float p = 0.f, qq = 0.f;
            #pragma unroll
            for (int nt = 0; nt < 4; ++nt) {
                const float v = acc[nt][r];
                if (node < N_NODES)
                    Wh[(size_t)node * F_OUT + nt * 16 + c16] = v;
                p  = fmaf(v, av[nt], p);
                qq = fmaf(v, av2[nt], qq);
            }
            #pragma unroll
            for (int off = 1; off <= 8; off <<= 1) {   // reduce over 16 cols
                p  += __shfl_xor(p, off);
                qq += __shfl_xor(qq, off);
            }
            if (c16 == 0 && node < N_NODES) { s_src[node] = p; s_dst[node] = qq; }
        }
    }
}

// ---------------------------------------------------------------------------
// Pass 1: LDS counting sort of 4096 edges by bucket (src>>6), then ONE global
// reservation per non-empty bin (~700 atomics/block vs 4096 per-edge), then
// run-contiguous copy-out (runs avg 5.2 -> line-packed writes). Entry packs
// bucket(10b) | src_local(6b) | dst(16b); top bits stripped on store.
// ---------------------------------------------------------------------------
__global__ __launch_bounds__(256) void gat_bucket(
    const int* __restrict__ edge, int* __restrict__ cnt,
    unsigned int* __restrict__ arr, int* __restrict__ of_cnt,
    int2* __restrict__ of_list)
{
    __shared__ int lhist[NBK];
    __shared__ int lstart[NBK + 1];
    __shared__ int gbase[NBK];
    __shared__ int cursor[NBK];
    __shared__ unsigned int sorted[EB];
    __shared__ int scanbuf[256];

    const int t   = threadIdx.x;
    const int blk = blockIdx.x;
    const int e0  = blk * EB;
    const int sub = blk & 7;

    for (int i = t; i < NBK; i += 256) lhist[i] = 0;
    __syncthreads();

    int sreg[EB / 256];
    #pragma unroll
    for (int i = 0; i < EB / 256; ++i) {
        const int e = e0 + i * 256 + t;
        int s = -1;
        if (e < N_EDGES) {
            s = edge[e];
            atomicAdd(&lhist[s >> 6], 1);
        }
        sreg[i] = s;
    }
    __syncthreads();

    // exclusive scan over 782 bins (thread t owns bins [4t,4t+4))
    int psum = 0;
    {
        const int b0 = t * 4;
        #pragma unroll
        for (int i = 0; i < 4; ++i)
            if (b0 + i < NBK) psum += lhist[b0 + i];
    }
    scanbuf[t] = psum;
    __syncthreads();
    for (int off = 1; off < 256; off <<= 1) {
        const int v = (t >= off) ? scanbuf[t - off] : 0;
        __syncthreads();
        scanbuf[t] += v;
        __syncthreads();
    }
    {
        int run = scanbuf[t] - psum;
        const int b0 = t * 4;
        #pragma unroll
        for (int i = 0; i < 4; ++i) {
            const int b = b0 + i;
            if (b < NBK) {
                lstart[b] = run;
                cursor[b] = run;
                run += lhist[b];
            }
        }
        if (t == 255) lstart[NBK] = scanbuf[255];
    }
    __syncthreads();

    // one global reservation per non-empty bin
    for (int b = t; b < NBK; b += 256) {
        const int c = lhist[b];
        gbase[b] = (c > 0) ? atomicAdd(&cnt[sub * NBK + b], c) : 0;
    }

    // sort-scatter into LDS
    #pragma unroll
    for (int i = 0; i < EB / 256; ++i) {
        const int s = sreg[i];
        if (s >= 0) {
            const int e = e0 + i * 256 + t;
            const int d = edge[N_EDGES + e];
            const int b = s >> 6;
            const int pos = atomicAdd(&cursor[b], 1);
            sorted[pos] = ((unsigned)b << 22) | ((unsigned)(s & 63) << 16) | (unsigned)d;
        }
    }
    __syncthreads();

    // run-contiguous copy-out
    const int C = lstart[NBK];
    for (int p = t; p < C; p += 256) {
        const unsigned en = sorted[p];
        const int b = (int)(en >> 22);
        const int idx = gbase[b] + (p - lstart[b]);
        if (idx < CAP) {
            arr[((size_t)(sub * NBK + b)) * CAP + idx] = en & 0x3FFFFFu;
        } else {
            const int s = b * 64 + (int)((en >> 16) & 63);
            const int op = atomicAdd(of_cnt, 1);
            if (op < OF_CAP) of_list[op] = make_int2(s, (int)(en & 0xFFFFu));
        }
    }
}

// ---------------------------------------------------------------------------
// Pass 2: block per 64-node bucket. LDS counting sort of ~2048 edges, then
// quarter-wave x float4 register aggregation (as R8). Wave handles 16 nodes.
// ---------------------------------------------------------------------------
__global__ __launch_bounds__(256) void gat_aggregate(
    const int* __restrict__ cnt, const unsigned int* __restrict__ arr,
    const float* __restrict__ s_src, const float* __restrict__ s_dst,
    const float* __restrict__ Wh, const int* __restrict__ of_cnt,
    const int2* __restrict__ of_list, float* __restrict__ out)
{
    __shared__ uint2 ent2[LDS_CAP];      // {dst, ee bits} — 20 KB
    __shared__ int   bin[BS];
    __shared__ int   start[BS + 1];
    __shared__ int   Pl[NSUB + 1];
    const int t = threadIdx.x;
    const int lane = t & 63;
    const int w = t >> 6;
    const int b = blockIdx.x;

    if (t < BS) bin[t] = 0;
    if (t == 0) {
        int run = 0;
        #pragma unroll
        for (int s2 = 0; s2 < NSUB; ++s2) {
            Pl[s2] = run;
            run += min(cnt[s2 * NBK + b], CAP);
        }
        Pl[NSUB] = run;
    }
    __syncthreads();
    const int C = Pl[NSUB];              // <= 3072
    const int nof = min(of_cnt[0], OF_CAP);

    unsigned enr[12];
    int nr = 0;
    for (int g = t; g < C; g += 256) {
        int sub = 0;
        #pragma unroll
        for (int s2 = 1; s2 < NSUB; ++s2) sub += (g >= Pl[s2]);
        const unsigned en = arr[((size_t)(sub * NBK + b)) * CAP + (g - Pl[sub])];
        enr[nr++] = en;
        atomicAdd(&bin[en >> 16], 1);
    }
    for (int i = t; i < nof; i += 256) {
        const int2 e2 = of_list[i];
        if ((e2.x >> 6) == b) atomicAdd(&bin[e2.x & 63], 1);
    }
    __syncthreads();
    if (t == 0) {
        int run = 0;
        #pragma unroll
        for (int n = 0; n < BS; ++n) {
            start[n] = run;
            run += bin[n];
            bin[n] = start[n];
        }
        start[BS] = run;
    }
    __syncthreads();

    for (int r = 0; r < nr; ++r) {
        const unsigned en = enr[r];
        const int sl = (int)(en >> 16);
        const int d  = (int)(en & 0xffffu);
        const float sc = s_src[b * BS + sl] + s_dst[d];
        const float ee = __expf(-(sc > 0.f ? sc : ALPHA * sc));
        const int pos = atomicAdd(&bin[sl], 1);
        if (pos < LDS_CAP) ent2[pos] = make_uint2((unsigned)d, __float_as_uint(ee));
    }
    for (int i = t; i < nof; i += 256) {
        const int2 e2 = of_list[i];
        if ((e2.x >> 6) == b) {
            const float sc = s_src[e2.x] + s_dst[e2.y];
            const float ee = __expf(-(sc > 0.f ? sc : ALPHA * sc));
            const int pos = atomicAdd(&bin[e2.x & 63], 1);
            if (pos < LDS_CAP) ent2[pos] = make_uint2((unsigned)e2.y, __float_as_uint(ee));
        }
    }
    __syncthreads();

    const int q  = lane >> 4;
    const int fq = lane & 15;
    const float4* __restrict__ Wh4 = (const float4*)Wh;

    for (int n = w * 16; n < w * 16 + 16; ++n) {
        const int node = b * BS + n;
        if (node >= N_NODES) break;
        const int r0 = start[n];
        const int r1 = min(start[n + 1], LDS_CAP);
        float4 acc = make_float4(0.f, 0.f, 0.f, 0.f);
        float rsum = 0.f;
        for (int j = r0; j < r1; j += 8) {
            const int ja = j + q;
            const int jb = j + 4 + q;
            const uint2 ea = ent2[min(ja, r1 - 1)];
            const uint2 eb = ent2[min(jb, r1 - 1)];
            const float eta = (ja < r1) ? __uint_as_float(ea.y) : 0.f;
            const float etb = (jb < r1) ? __uint_as_float(eb.y) : 0.f;
            const float4 wa = Wh4[(size_t)ea.x * 16 + fq];
            const float4 wb = Wh4[(size_t)eb.x * 16 + fq];
            acc.x = fmaf(eta, wa.x, acc.x); acc.y = fmaf(eta, wa.y, acc.y);
            acc.z = fmaf(eta, wa.z, acc.z); acc.w = fmaf(eta, wa.w, acc.w);
            acc.x = fmaf(etb, wb.x, acc.x); acc.y = fmaf(etb, wb.y, acc.y);
            acc.z = fmaf(etb, wb.z, acc.z); acc.w = fmaf(etb, wb.w, acc.w);
            rsum += eta + etb;
        }
        acc.x += __shfl_xor(acc.x, 16); acc.x += __shfl_xor(acc.x, 32);
        acc.y += __shfl_xor(acc.y, 16); acc.y += __shfl_xor(acc.y, 32);
        acc.z += __shfl_xor(acc.z, 16); acc.z += __shfl_xor(acc.z, 32);
        acc.w += __shfl_xor(acc.w, 16); acc.w += __shfl_xor(acc.w, 32);
        rsum  += __shfl_xor(rsum, 16);  rsum  += __shfl_xor(rsum, 32);

        float4 v;
        v.x = acc.x / rsum; v.y = acc.y / rsum;
        v.z = acc.z / rsum; v.w = acc.w / rsum;
        v.x = v.x > 0.f ? v.x : (__expf(v.x) - 1.f);
        v.y = v.y > 0.f ? v.y : (__expf(v.y) - 1.f);
        v.z = v.z > 0.f ? v.z : (__expf(v.z) - 1.f);
        v.w = v.w > 0.f ? v.w : (__expf(v.w) - 1.f);
        if (q == 0)
            ((float4*)out)[(size_t)node * 16 + fq] = v;
    }
}

extern "C" void kernel_launch(void* const* d_in, const int* in_sizes, int n_in,
                              void* d_out, int out_size, void* d_ws, size_t ws_size,
                              hipStream_t stream) {
    const float* x    = (const float*)d_in[0];
    const int*   edge = (const int*)  d_in[1];
    const float* W    = (const float*)d_in[2];
    const float* a    = (const float*)d_in[3];
    float* out = (float*)d_out;

    float* ws = (float*)d_ws;
    float*          Wh      = ws;                                      // 3,200,000 f
    unsigned int*   arr     = (unsigned int*)(Wh + (size_t)N_NODES * F_OUT);
    float*          s_src   = (float*)(arr + (size_t)NSUB * NBK * CAP); // 50,000 f
    float*          s_dst   = s_src + N_NODES;                          // 50,000 f
    int*            cnt     = (int*)(s_dst + N_NODES);                  // 6,256 i
    int2*           of_list = (int2*)(cnt + NSUB * NBK);                // 8B-aligned
    int*            of_cnt  = (int*)(of_list + OF_CAP);                 // 1 i + pad 3
    unsigned short* Wf      = (unsigned short*)(of_cnt + 4);            // 16,384 us (16B-aligned)

    hipMemsetAsync(cnt, 0, (size_t)NSUB * NBK * sizeof(int), stream);
    hipMemsetAsync(of_cnt, 0, sizeof(int), stream);

    gat_wprep<<<1, 256, 0, stream>>>(W, Wf);
    gat_gemm<<<391, 256, 0, stream>>>(x, Wf, a, Wh, s_src, s_dst);
    gat_bucket<<<NBB, 256, 0, stream>>>(edge, cnt, arr, of_cnt, of_list);
    gat_aggregate<<<NBK, 256, 0, stream>>>(cnt, arr, s_src, s_dst, Wh,
                                           of_cnt, of_list, out);
}

// Round 10
// 189.245 us; speedup vs baseline: 5.1705x; 1.0386x over previous
//
#include <hip/hip_runtime.h>

#define N_NODES 50000
#define N_EDGES 1600000
#define F_IN 256
#define F_OUT 64
#define ALPHA 0.2f

#define BS 64                 // nodes per bucket
#define NBK 782               // ceil(50000/64)
#define NSUB 8                // sub-buckets keyed by blockIdx&7
#define CAP 384               // per (sub,bucket) capacity; mean 256, sd ~15
#define EB 4096               // edges per bucket-sort block
#define NBB 391               // ceil(E/EB)
#define LDS_CAP 2560          // per-bucket LDS edge cap; mean 2048, sd ~45
#define OF_CAP 16384          // overflow list (normally empty)

typedef __attribute__((ext_vector_type(8))) short bf16x8;
typedef __attribute__((ext_vector_type(4))) float f32x4;

__device__ inline unsigned short f2bf(float f) {   // RNE fp32->bf16
    unsigned int u = __float_as_uint(f);
    return (unsigned short)((u + 0x7FFFu + ((u >> 16) & 1u)) >> 16);
}
__device__ inline float bf2f(unsigned short b) {
    return __uint_as_float(((unsigned int)b) << 16);
}

// ---------------------------------------------------------------------------
// W prepack: W fp32 -> bf16 in MFMA B-frag order (64 blocks, 256 elems each).
// ---------------------------------------------------------------------------
__global__ __launch_bounds__(256) void gat_wprep(
    const float* __restrict__ W, unsigned short* __restrict__ Wf)
{
    const int di = blockIdx.x * 256 + threadIdx.x;   // < 16384
    const int j    = di & 7;
    const int lane = (di >> 3) & 63;
    const int tile = di >> 9;           // ks*4 + nt
    const int ks   = tile >> 2;
    const int nt   = tile & 3;
    const int k = ks * 32 + (lane >> 4) * 8 + j;
    const int n = nt * 16 + (lane & 15);
    Wf[di] = f2bf(W[k * F_OUT + n]);
}

// ---------------------------------------------------------------------------
// Kernel A: Wh = x @ W via bf16 MFMA 16x16x32, 2-term precision split.
// (Verified R9: absmax 0.031.) Grid bumped 391->782 (3 blocks/CU).
// ---------------------------------------------------------------------------
__global__ __launch_bounds__(256) void gat_gemm(
    const float* __restrict__ x, const unsigned short* __restrict__ Wf,
    const float* __restrict__ a, float* __restrict__ Wh,
    float* __restrict__ s_src, float* __restrict__ s_dst)
{
    __shared__ unsigned short Wl[F_IN * F_OUT];   // 32 KB, frag-ordered bf16
    const int t = threadIdx.x;
    {
        const float4* __restrict__ src = (const float4*)Wf;
        float4* dst = (float4*)Wl;
        #pragma unroll
        for (int i = 0; i < 8; ++i) dst[t + i * 256] = src[t + i * 256];
    }
    __syncthreads();

    const int lane = t & 63;
    const int w    = t >> 6;
    const int q    = lane >> 4;
    const int c16  = lane & 15;
    const bf16x8* __restrict__ Wfrag = (const bf16x8*)Wl;  // [(ks*4+nt)*64+lane]

    float av[4], av2[4];
    #pragma unroll
    for (int nt = 0; nt < 4; ++nt) {
        av[nt]  = a[nt * 16 + c16];
        av2[nt] = a[F_OUT + nt * 16 + c16];
    }

    for (int c = blockIdx.x; c < NBK; c += gridDim.x) {
        const int node0 = c * 64 + w * 16;
        int row = node0 + c16;                   // A m-index = lane&15
        if (row >= N_NODES) row = N_NODES - 1;   // clamp; ghost stores guarded
        const float4* __restrict__ xp = (const float4*)(x + (size_t)row * F_IN);

        float4 xv[16];
        #pragma unroll
        for (int ks = 0; ks < 8; ++ks) {         // k = ks*32 + q*8 + j
            xv[2 * ks]     = xp[ks * 8 + q * 2];
            xv[2 * ks + 1] = xp[ks * 8 + q * 2 + 1];
        }

        f32x4 acc[4];
        #pragma unroll
        for (int nt = 0; nt < 4; ++nt) acc[nt] = (f32x4){0.f, 0.f, 0.f, 0.f};

        #pragma unroll
        for (int ks = 0; ks < 8; ++ks) {
            float xf[8] = {xv[2*ks].x,   xv[2*ks].y,   xv[2*ks].z,   xv[2*ks].w,
                           xv[2*ks+1].x, xv[2*ks+1].y, xv[2*ks+1].z, xv[2*ks+1].w};
            bf16x8 ah, al;
            #pragma unroll
            for (int j = 0; j < 8; ++j) {
                const unsigned short h = f2bf(xf[j]);
                ah[j] = (short)h;
                al[j] = (short)f2bf(xf[j] - bf2f(h));
            }
            #pragma unroll
            for (int nt = 0; nt < 4; ++nt) {
                const bf16x8 bh = Wfrag[(ks * 4 + nt) * 64 + lane];
                acc[nt] = __builtin_amdgcn_mfma_f32_16x16x32_bf16(ah, bh, acc[nt], 0, 0, 0);
                acc[nt] = __builtin_amdgcn_mfma_f32_16x16x32_bf16(al, bh, acc[nt], 0, 0, 0);
            }
        }

        #pragma unroll
        for (int r = 0; r < 4; ++r) {
            const int node = node0 + q * 4 + r;  // C row = (l>>4)*4 + reg
            float p = 0.f, qq = 0.f;
            #pragma unroll
            for (int nt = 0; nt < 4; ++nt) {
                const float v = acc[nt][r];
                if (node < N_NODES)
                    Wh[(size_t)node * F_OUT + nt * 16 + c16] = v;
                p  = fmaf(v, av[nt], p);
                qq = fmaf(v, av2[nt], qq);
            }
            #pragma unroll
            for (int off = 1; off <= 8; off <<= 1) {   // reduce over 16 cols
                p  += __shfl_xor(p, off);
                qq += __shfl_xor(qq, off);
            }
            if (c16 == 0 && node < N_NODES) { s_src[node] = p; s_dst[node] = qq; }
        }
    }
}

// ---------------------------------------------------------------------------
// Pass 1: LDS counting sort of 4096 edges by bucket (src>>6), one global
// reservation per non-empty bin, run-contiguous copy-out. (Unchanged R9.)
// ---------------------------------------------------------------------------
__global__ __launch_bounds__(256) void gat_bucket(
    const int* __restrict__ edge, int* __restrict__ cnt,
    unsigned int* __restrict__ arr, int* __restrict__ of_cnt,
    int2* __restrict__ of_list)
{
    __shared__ int lhist[NBK];
    __shared__ int lstart[NBK + 1];
    __shared__ int gbase[NBK];
    __shared__ int cursor[NBK];
    __shared__ unsigned int sorted[EB];
    __shared__ int scanbuf[256];

    const int t   = threadIdx.x;
    const int blk = blockIdx.x;
    const int e0  = blk * EB;
    const int sub = blk & 7;

    for (int i = t; i < NBK; i += 256) lhist[i] = 0;
    __syncthreads();

    int sreg[EB / 256];
    #pragma unroll
    for (int i = 0; i < EB / 256; ++i) {
        const int e = e0 + i * 256 + t;
        int s = -1;
        if (e < N_EDGES) {
            s = edge[e];
            atomicAdd(&lhist[s >> 6], 1);
        }
        sreg[i] = s;
    }
    __syncthreads();

    int psum = 0;
    {
        const int b0 = t * 4;
        #pragma unroll
        for (int i = 0; i < 4; ++i)
            if (b0 + i < NBK) psum += lhist[b0 + i];
    }
    scanbuf[t] = psum;
    __syncthreads();
    for (int off = 1; off < 256; off <<= 1) {
        const int v = (t >= off) ? scanbuf[t - off] : 0;
        __syncthreads();
        scanbuf[t] += v;
        __syncthreads();
    }
    {
        int run = scanbuf[t] - psum;
        const int b0 = t * 4;
        #pragma unroll
        for (int i = 0; i < 4; ++i) {
            const int b = b0 + i;
            if (b < NBK) {
                lstart[b] = run;
                cursor[b] = run;
                run += lhist[b];
            }
        }
        if (t == 255) lstart[NBK] = scanbuf[255];
    }
    __syncthreads();

    for (int b = t; b < NBK; b += 256) {
        const int c = lhist[b];
        gbase[b] = (c > 0) ? atomicAdd(&cnt[sub * NBK + b], c) : 0;
    }

    #pragma unroll
    for (int i = 0; i < EB / 256; ++i) {
        const int s = sreg[i];
        if (s >= 0) {
            const int e = e0 + i * 256 + t;
            const int d = edge[N_EDGES + e];
            const int b = s >> 6;
            const int pos = atomicAdd(&cursor[b], 1);
            sorted[pos] = ((unsigned)b << 22) | ((unsigned)(s & 63) << 16) | (unsigned)d;
        }
    }
    __syncthreads();

    const int C = lstart[NBK];
    for (int p = t; p < C; p += 256) {
        const unsigned en = sorted[p];
        const int b = (int)(en >> 22);
        const int idx = gbase[b] + (p - lstart[b]);
        if (idx < CAP) {
            arr[((size_t)(sub * NBK + b)) * CAP + idx] = en & 0x3FFFFFu;
        } else {
            const int s = b * 64 + (int)((en >> 16) & 63);
            const int op = atomicAdd(of_cnt, 1);
            if (op < OF_CAP) of_list[op] = make_int2(s, (int)(en & 0xFFFFu));
        }
    }
}

// ---------------------------------------------------------------------------
// Pass 2: block per 64-node bucket, now 512 THREADS (R9 was 256: grid 782
// => only 3 blocks/CU => 12 waves/CU, Occupancy 28%, latency-bound at 31%
// VALUBusy). 8 waves/block => 24 waves/CU resident. Inner loop widened to
// 16 edges/iter (4 ds_read_b64 + 4 dwordx4 in flight). Wave handles 8 nodes.
// ---------------------------------------------------------------------------
__global__ __launch_bounds__(512) void gat_aggregate(
    const int* __restrict__ cnt, const unsigned int* __restrict__ arr,
    const float* __restrict__ s_src, const float* __restrict__ s_dst,
    const float* __restrict__ Wh, const int* __restrict__ of_cnt,
    const int2* __restrict__ of_list, float* __restrict__ out)
{
    __shared__ uint2 ent2[LDS_CAP];      // {dst, ee bits} — 20 KB
    __shared__ int   bin[BS];
    __shared__ int   start[BS + 1];
    __shared__ int   Pl[NSUB + 1];
    const int t = threadIdx.x;
    const int lane = t & 63;
    const int w = t >> 6;                // 0..7
    const int b = blockIdx.x;

    if (t < BS) bin[t] = 0;
    if (t == 0) {
        int run = 0;
        #pragma unroll
        for (int s2 = 0; s2 < NSUB; ++s2) {
            Pl[s2] = run;
            run += min(cnt[s2 * NBK + b], CAP);
        }
        Pl[NSUB] = run;
    }
    __syncthreads();
    const int C = Pl[NSUB];              // <= 3072
    const int nof = min(of_cnt[0], OF_CAP);

    unsigned enr[6];
    int nr = 0;
    for (int g = t; g < C; g += 512) {
        int sub = 0;
        #pragma unroll
        for (int s2 = 1; s2 < NSUB; ++s2) sub += (g >= Pl[s2]);
        const unsigned en = arr[((size_t)(sub * NBK + b)) * CAP + (g - Pl[sub])];
        enr[nr++] = en;
        atomicAdd(&bin[en >> 16], 1);
    }
    for (int i = t; i < nof; i += 512) {
        const int2 e2 = of_list[i];
        if ((e2.x >> 6) == b) atomicAdd(&bin[e2.x & 63], 1);
    }
    __syncthreads();
    if (t == 0) {
        int run = 0;
        #pragma unroll
        for (int n = 0; n < BS; ++n) {
            start[n] = run;
            run += bin[n];
            bin[n] = start[n];
        }
        start[BS] = run;
    }
    __syncthreads();

    for (int r = 0; r < nr; ++r) {
        const unsigned en = enr[r];
        const int sl = (int)(en >> 16);
        const int d  = (int)(en & 0xffffu);
        const float sc = s_src[b * BS + sl] + s_dst[d];
        const float ee = __expf(-(sc > 0.f ? sc : ALPHA * sc));
        const int pos = atomicAdd(&bin[sl], 1);
        if (pos < LDS_CAP) ent2[pos] = make_uint2((unsigned)d, __float_as_uint(ee));
    }
    for (int i = t; i < nof; i += 512) {
        const int2 e2 = of_list[i];
        if ((e2.x >> 6) == b) {
            const float sc = s_src[e2.x] + s_dst[e2.y];
            const float ee = __expf(-(sc > 0.f ? sc : ALPHA * sc));
            const int pos = atomicAdd(&bin[e2.x & 63], 1);
            if (pos < LDS_CAP) ent2[pos] = make_uint2((unsigned)e2.y, __float_as_uint(ee));
        }
    }
    __syncthreads();

    const int q  = lane >> 4;
    const int fq = lane & 15;
    const float4* __restrict__ Wh4 = (const float4*)Wh;

    for (int n = w * 8; n < w * 8 + 8; ++n) {
        const int node = b * BS + n;
        if (node >= N_NODES) break;
        const int r0 = start[n];
        const int r1 = min(start[n + 1], LDS_CAP);
        float4 acc = make_float4(0.f, 0.f, 0.f, 0.f);
        float rsum = 0.f;
        for (int j = r0; j < r1; j += 16) {
            const int ja = j + q;
            const int jb = j + 4 + q;
            const int jc = j + 8 + q;
            const int jd = j + 12 + q;
            const uint2 ea = ent2[min(ja, r1 - 1)];
            const uint2 eb = ent2[min(jb, r1 - 1)];
            const uint2 ec = ent2[min(jc, r1 - 1)];
            const uint2 ed = ent2[min(jd, r1 - 1)];
            const float eta = (ja < r1) ? __uint_as_float(ea.y) : 0.f;
            const float etb = (jb < r1) ? __uint_as_float(eb.y) : 0.f;
            const float etc = (jc < r1) ? __uint_as_float(ec.y) : 0.f;
            const float etd = (jd < r1) ? __uint_as_float(ed.y) : 0.f;
            const float4 wa = Wh4[(size_t)ea.x * 16 + fq];
            const float4 wb = Wh4[(size_t)eb.x * 16 + fq];
            const float4 wc = Wh4[(size_t)ec.x * 16 + fq];
            const float4 wd = Wh4[(size_t)ed.x * 16 + fq];
            acc.x = fmaf(eta, wa.x, acc.x); acc.y = fmaf(eta, wa.y, acc.y);
            acc.z = fmaf(eta, wa.z, acc.z); acc.w = fmaf(eta, wa.w, acc.w);
            acc.x = fmaf(etb, wb.x, acc.x); acc.y = fmaf(etb, wb.y, acc.y);
            acc.z = fmaf(etb, wb.z, acc.z); acc.w = fmaf(etb, wb.w, acc.w);
            acc.x = fmaf(etc, wc.x, acc.x); acc.y = fmaf(etc, wc.y, acc.y);
            acc.z = fmaf(etc, wc.z, acc.z); acc.w = fmaf(etc, wc.w, acc.w);
            acc.x = fmaf(etd, wd.x, acc.x); acc.y = fmaf(etd, wd.y, acc.y);
            acc.z = fmaf(etd, wd.z, acc.z); acc.w = fmaf(etd, wd.w, acc.w);
            rsum += (eta + etb) + (etc + etd);
        }
        acc.x += __shfl_xor(acc.x, 16); acc.x += __shfl_xor(acc.x, 32);
        acc.y += __shfl_xor(acc.y, 16); acc.y += __shfl_xor(acc.y, 32);
        acc.z += __shfl_xor(acc.z, 16); acc.z += __shfl_xor(acc.z, 32);
        acc.w += __shfl_xor(acc.w, 16); acc.w += __shfl_xor(acc.w, 32);
        rsum  += __shfl_xor(rsum, 16);  rsum  += __shfl_xor(rsum, 32);

        float4 v;
        v.x = acc.x / rsum; v.y = acc.y / rsum;
        v.z = acc.z / rsum; v.w = acc.w / rsum;
        v.x = v.x > 0.f ? v.x : (__expf(v.x) - 1.f);
        v.y = v.y > 0.f ? v.y : (__expf(v.y) - 1.f);
        v.z = v.z > 0.f ? v.z : (__expf(v.z) - 1.f);
        v.w = v.w > 0.f ? v.w : (__expf(v.w) - 1.f);
        if (q == 0)
            ((float4*)out)[(size_t)node * 16 + fq] = v;
    }
}

extern "C" void kernel_launch(void* const* d_in, const int* in_sizes, int n_in,
                              void* d_out, int out_size, void* d_ws, size_t ws_size,
                              hipStream_t stream) {
    const float* x    = (const float*)d_in[0];
    const int*   edge = (const int*)  d_in[1];
    const float* W    = (const float*)d_in[2];
    const float* a    = (const float*)d_in[3];
    float* out = (float*)d_out;

    float* ws = (float*)d_ws;
    float*          Wh      = ws;                                      // 3,200,000 f
    unsigned int*   arr     = (unsigned int*)(Wh + (size_t)N_NODES * F_OUT);
    float*          s_src   = (float*)(arr + (size_t)NSUB * NBK * CAP); // 50,000 f
    float*          s_dst   = s_src + N_NODES;                          // 50,000 f
    int*            cnt     = (int*)(s_dst + N_NODES);                  // 6,256 i
    int2*           of_list = (int2*)(cnt + NSUB * NBK);                // 8B-aligned
    int*            of_cnt  = (int*)(of_list + OF_CAP);                 // 1 i + pad 3
    unsigned short* Wf      = (unsigned short*)(of_cnt + 4);            // 16,384 us (16B-aligned)

    hipMemsetAsync(cnt, 0, (size_t)NSUB * NBK * sizeof(int), stream);
    hipMemsetAsync(of_cnt, 0, sizeof(int), stream);

    gat_wprep<<<64, 256, 0, stream>>>(W, Wf);
    gat_gemm<<<782, 256, 0, stream>>>(x, Wf, a, Wh, s_src, s_dst);
    gat_bucket<<<NBB, 256, 0, stream>>>(edge, cnt, arr, of_cnt, of_list);
    gat_aggregate<<<NBK, 512, 0, stream>>>(cnt, arr, s_src, s_dst, Wh,
                                           of_cnt, of_list, out);
}